// Round 1
// baseline (159.194 us; speedup 1.0000x reference)
//
#include <hip/hip_runtime.h>

#define NEG_SLOPE 0.2f
#define MASK_EPS 1e-8f
#define NEG_INF -1000000000.0f

// ---------------------------------------------------------------------------
// Kernel 1: Wh = h @ W  (B*N=16384 rows, K=128, D_out=128)
//           s_i[row,h] = dot(Wh[row, h*32:(h+1)*32], a_src[h])
//           s_j[row,h] = dot(Wh[row, h*32:(h+1)*32], a_dst[h])
// Block: 256 threads = 8 rows x 32 col-groups (4 cols each).
// ---------------------------------------------------------------------------
__global__ __launch_bounds__(256) void gat_wh_kernel(
    const float* __restrict__ h, const float* __restrict__ W,
    const float* __restrict__ a, float* __restrict__ Wh,
    float* __restrict__ sI, float* __restrict__ sJ) {
  __shared__ float hS[8][128];
  const int tid = threadIdx.x;
  const int row0 = blockIdx.x * 8;

  // stage 8 rows of h (one float4 per thread)
  {
    int r = tid >> 5, c4 = (tid & 31) << 2;
    *(float4*)&hS[r][c4] = *(const float4*)&h[(size_t)(row0 + r) * 128 + c4];
  }
  __syncthreads();

  const int rowl = tid >> 5;
  const int cidx = tid & 31;
  const int c0 = cidx << 2;

  float4 acc = {0.f, 0.f, 0.f, 0.f};
#pragma unroll 8
  for (int k = 0; k < 128; ++k) {
    float hv = hS[rowl][k];
    float4 w4 = *(const float4*)&W[k * 128 + c0];
    acc.x = fmaf(hv, w4.x, acc.x);
    acc.y = fmaf(hv, w4.y, acc.y);
    acc.z = fmaf(hv, w4.z, acc.z);
    acc.w = fmaf(hv, w4.w, acc.w);
  }

  const size_t row = (size_t)row0 + rowl;
  *(float4*)&Wh[row * 128 + c0] = acc;

  // head score partials
  const int head = cidx >> 3;        // c0 / 32
  const int dl = c0 & 31;            // d within head
  const float* asrc = &a[head * 64];
  const float* adst = &a[head * 64 + 32];
  float pi = acc.x * asrc[dl] + acc.y * asrc[dl + 1] + acc.z * asrc[dl + 2] + acc.w * asrc[dl + 3];
  float pj = acc.x * adst[dl] + acc.y * adst[dl + 1] + acc.z * adst[dl + 2] + acc.w * adst[dl + 3];
#pragma unroll
  for (int off = 1; off < 8; off <<= 1) {
    pi += __shfl_xor(pi, off, 64);
    pj += __shfl_xor(pj, off, 64);
  }
  if ((cidx & 7) == 0) {
    sI[row * 4 + head] = pi;
    sJ[row * 4 + head] = pj;
  }
}

// ---------------------------------------------------------------------------
// Kernel 2: per (b, j-tile of 64): two-pass masked softmax over i (512) and
// weighted aggregation of Wh rows. Thread = (h, jl): tid = h*64 + jl.
// Pass 1: m = max_i ev ; Pass 2: l = sum exp(ev-m), acc += p * Wh[i,h,:].
// ---------------------------------------------------------------------------
__global__ __launch_bounds__(256) void gat_attn_kernel(
    const float* __restrict__ adj, const float* __restrict__ Wh,
    const float* __restrict__ sI, const float* __restrict__ sJ,
    float* __restrict__ out) {
  __shared__ float sIS[512 * 4];     // 8 KB  [i*4 + h]
  __shared__ float adjS[64][64];     // 16 KB
  __shared__ float whS[64][128];     // 32 KB

  const int tid = threadIdx.x;
  const int b = blockIdx.x;          // 0..31
  const int j0 = blockIdx.y * 64;    // 8 tiles
  const int h = tid >> 6;            // wave id = head
  const int jl = tid & 63;
  const int j = j0 + jl;

  for (int idx = tid; idx < 2048; idx += 256)
    sIS[idx] = sI[(size_t)b * 2048 + idx];
  const float sJv = sJ[((size_t)b * 512 + j) * 4 + h];
  __syncthreads();

  const float* adjB = adj + (size_t)b * 512 * 512;
  const float* WhB = Wh + (size_t)b * 512 * 128;

  // ---- Pass 1: masked max over i ----
  float m = -INFINITY;
  for (int c = 0; c < 8; ++c) {
    __syncthreads();
    for (int idx = tid; idx < 64 * 16; idx += 256) {
      int r = idx >> 4, c4 = (idx & 15) << 2;
      *(float4*)&adjS[r][c4] = *(const float4*)&adjB[(size_t)(c * 64 + r) * 512 + j0 + c4];
    }
    __syncthreads();
#pragma unroll 8
    for (int ii = 0; ii < 64; ++ii) {
      float e = sIS[(c * 64 + ii) * 4 + h] + sJv;
      e = e >= 0.f ? e : NEG_SLOPE * e;
      float ev = adjS[ii][jl] > MASK_EPS ? e : NEG_INF;
      m = fmaxf(m, ev);
    }
  }

  // ---- Pass 2: exp-sum + weighted accumulate ----
  float l = 0.f;
  float4 acc[8];
#pragma unroll
  for (int q = 0; q < 8; ++q) acc[q] = make_float4(0.f, 0.f, 0.f, 0.f);

  for (int c = 0; c < 8; ++c) {
    __syncthreads();
    for (int idx = tid; idx < 64 * 16; idx += 256) {
      int r = idx >> 4, c4 = (idx & 15) << 2;
      *(float4*)&adjS[r][c4] = *(const float4*)&adjB[(size_t)(c * 64 + r) * 512 + j0 + c4];
    }
    for (int idx = tid; idx < 64 * 32; idx += 256) {
      int r = idx >> 5, c4 = (idx & 31) << 2;
      *(float4*)&whS[r][c4] = *(const float4*)&WhB[(size_t)(c * 64 + r) * 128 + c4];
    }
    __syncthreads();
    for (int ii = 0; ii < 64; ++ii) {
      float e = sIS[(c * 64 + ii) * 4 + h] + sJv;
      e = e >= 0.f ? e : NEG_SLOPE * e;
      float ev = adjS[ii][jl] > MASK_EPS ? e : NEG_INF;
      float p = __expf(ev - m);
      l += p;
      const float4* wrow = (const float4*)&whS[ii][h * 32];
#pragma unroll
      for (int q = 0; q < 8; ++q) {
        float4 w = wrow[q];
        acc[q].x = fmaf(p, w.x, acc[q].x);
        acc[q].y = fmaf(p, w.y, acc[q].y);
        acc[q].z = fmaf(p, w.z, acc[q].z);
        acc[q].w = fmaf(p, w.w, acc[q].w);
      }
    }
  }

  const float rl = 1.0f / l;
  float* orow = &out[((size_t)b * 512 + j) * 128 + h * 32];
#pragma unroll
  for (int q = 0; q < 8; ++q) {
    float4 v = make_float4(acc[q].x * rl, acc[q].y * rl, acc[q].z * rl, acc[q].w * rl);
    *(float4*)&orow[q * 4] = v;
  }
}

extern "C" void kernel_launch(void* const* d_in, const int* in_sizes, int n_in,
                              void* d_out, int out_size, void* d_ws, size_t ws_size,
                              hipStream_t stream) {
  const float* h = (const float*)d_in[0];     // (32, 512, 128)
  const float* adj = (const float*)d_in[1];   // (32, 512, 512)
  const float* W = (const float*)d_in[2];     // (128, 128)
  const float* a = (const float*)d_in[3];     // (4, 64)
  float* out = (float*)d_out;                 // (32, 512, 128)

  const int B = 32, N = 512, D = 128, H = 4;
  float* Wh = (float*)d_ws;                   // B*N*D floats = 8 MB
  float* sI = Wh + (size_t)B * N * D;         // B*N*H floats
  float* sJ = sI + (size_t)B * N * H;

  gat_wh_kernel<<<dim3(B * N / 8), dim3(256), 0, stream>>>(h, W, a, Wh, sI, sJ);
  gat_attn_kernel<<<dim3(B, N / 64), dim3(256), 0, stream>>>(adj, Wh, sI, sJ, out);
}